// Round 1
// baseline (428.753 us; speedup 1.0000x reference)
//
#include <hip/hip_runtime.h>
#include <cfloat>

#define P_TOT     4194304      // 8*512*1024 pixels
#define HW_       524288       // 512*1024
#define NCLS      19
#define IGNORE_IDX 255
#define MIN_KEPT_ 100000
#define NBLK      4096         // pass1 blocks: 4096*256*4 = P_TOT exactly
#define THR       0.7f

__device__ __forceinline__ double wred_d(double v){
  #pragma unroll
  for (int o = 32; o > 0; o >>= 1) v += __shfl_down(v, o, 64);
  return v;
}
__device__ __forceinline__ unsigned wred_u(unsigned v){
  #pragma unroll
  for (int o = 32; o > 0; o >>= 1) v += __shfl_down(v, o, 64);
  return v;
}

// Pass 1: fused log-softmax-at-label + per-block reductions.
// Each thread: 4 consecutive pixels via float4 loads (19 coalesced plane reads).
__global__ __launch_bounds__(256) void ohem_pass1(
    const float* __restrict__ logits, const int* __restrict__ tgt,
    double* __restrict__ p_sle, double* __restrict__ p_sva,
    unsigned* __restrict__ p_cle, unsigned* __restrict__ p_cva)
{
  int tid = blockIdx.x * 256 + threadIdx.x;
  int p0  = tid * 4;
  int n   = p0 >> 19;              // p0 / HW_
  int r   = p0 & (HW_ - 1);
  const float* base = logits + (size_t)n * (NCLS * (size_t)HW_) + r;

  int4 tl = *(const int4*)(tgt + p0);
  int lab0 = tl.x, lab1 = tl.y, lab2 = tl.z, lab3 = tl.w;

  float4 vals[NCLS];
  float4 mx, xl;
  xl.x = xl.y = xl.z = xl.w = 0.f;
  mx.x = mx.y = mx.z = mx.w = -FLT_MAX;
  #pragma unroll
  for (int c = 0; c < NCLS; c++){
    float4 v = *(const float4*)(base + (size_t)c * HW_);
    vals[c] = v;
    mx.x = fmaxf(mx.x, v.x); mx.y = fmaxf(mx.y, v.y);
    mx.z = fmaxf(mx.z, v.z); mx.w = fmaxf(mx.w, v.w);
    xl.x = (lab0 == c) ? v.x : xl.x;
    xl.y = (lab1 == c) ? v.y : xl.y;
    xl.z = (lab2 == c) ? v.z : xl.z;
    xl.w = (lab3 == c) ? v.w : xl.w;
  }
  float4 se; se.x = se.y = se.z = se.w = 0.f;
  #pragma unroll
  for (int c = 0; c < NCLS; c++){
    se.x += __expf(vals[c].x - mx.x);
    se.y += __expf(vals[c].y - mx.y);
    se.z += __expf(vals[c].z - mx.z);
    se.w += __expf(vals[c].w - mx.w);
  }

  double sle = 0.0, sva = 0.0; unsigned cle = 0, cva = 0;
  #define PIXEL(comp, LAB) {                                   \
    float lp = (xl.comp - mx.comp) - __logf(se.comp);          \
    float pd = __expf(lp);                                     \
    if (LAB != IGNORE_IDX){                                    \
      cva++; sva += (double)lp;                                \
      if (pd <= THR){ cle++; sle += (double)lp; }              \
    }                                                          \
  }
  PIXEL(x, lab0) PIXEL(y, lab1) PIXEL(z, lab2) PIXEL(w, lab3)
  #undef PIXEL

  sle = wred_d(sle); sva = wred_d(sva);
  cle = wred_u(cle); cva = wred_u(cva);

  __shared__ double  ls1[4], ls2[4];
  __shared__ unsigned lc1[4], lc2[4];
  int wv = threadIdx.x >> 6, ln = threadIdx.x & 63;
  if (ln == 0){ ls1[wv] = sle; ls2[wv] = sva; lc1[wv] = cle; lc2[wv] = cva; }
  __syncthreads();
  if (threadIdx.x == 0){
    double a = ls1[0] + ls1[1] + ls1[2] + ls1[3];
    double b = ls2[0] + ls2[1] + ls2[2] + ls2[3];
    unsigned c1 = lc1[0] + lc1[1] + lc1[2] + lc1[3];
    unsigned c2 = lc2[0] + lc2[1] + lc2[2] + lc2[3];
    p_sle[blockIdx.x] = a; p_sva[blockIdx.x] = b;
    p_cle[blockIdx.x] = c1; p_cva[blockIdx.x] = c2;
  }
}

// Finish: reduce partials, resolve the three OHEM cases.
// Cold fallback (exact bitwise radix-select of the kth-smallest pred) only
// runs when count(valid & pred<=0.7) < MIN_KEPT < num_valid — never for the
// bench distribution, but kept for full correctness.
__global__ __launch_bounds__(1024) void ohem_finish(
    const float* __restrict__ logits, const int* __restrict__ tgt,
    const double* __restrict__ p_sle, const double* __restrict__ p_sva,
    const unsigned* __restrict__ p_cle, const unsigned* __restrict__ p_cva,
    unsigned* __restrict__ keys, float* __restrict__ logp,
    float* __restrict__ out)
{
  __shared__ double  rs1[16], rs2[16];
  __shared__ unsigned rc1[16], rc2[16];
  __shared__ unsigned s_flag, s_prefix, s_rank;
  __shared__ unsigned s_hist[4096];

  int t = threadIdx.x;
  double sle = 0.0, sva = 0.0; unsigned cle = 0, cva = 0;
  for (int i = t; i < NBLK; i += 1024){
    sle += p_sle[i]; sva += p_sva[i]; cle += p_cle[i]; cva += p_cva[i];
  }
  sle = wred_d(sle); sva = wred_d(sva);
  cle = wred_u(cle); cva = wred_u(cva);
  int wv = t >> 6, ln = t & 63;
  if (ln == 0){ rs1[wv] = sle; rs2[wv] = sva; rc1[wv] = cle; rc2[wv] = cva; }
  __syncthreads();
  if (t == 0){
    double S1 = 0, S2 = 0; unsigned C1 = 0, C2 = 0;
    for (int i = 0; i < 16; i++){ S1 += rs1[i]; S2 += rs2[i]; C1 += rc1[i]; C2 += rc2[i]; }
    unsigned flag;
    if (C2 <= MIN_KEPT_){                       // do_ohem false: keep all valid
      unsigned d = C2 > 1u ? C2 : 1u;
      out[0] = (float)(-S2 / (double)d);
      flag = 0;
    } else if (C1 >= MIN_KEPT_){                // kth <= 0.7 => threshold = 0.7
      out[0] = (float)(-S1 / (double)C1);
      flag = 0;
    } else flag = 1;                            // need exact kth (> 0.7)
    s_flag = flag;
  }
  __syncthreads();
  if (!s_flag) return;

  // ---------- cold fallback: exact selection ----------
  for (int p = t; p < P_TOT; p += 1024){
    int n = p >> 19; int r = p & (HW_ - 1);
    const float* bp = logits + (size_t)n * (NCLS * (size_t)HW_) + r;
    int lab = tgt[p];
    float mxv = -FLT_MAX, xlv = 0.f, va[NCLS];
    #pragma unroll
    for (int c = 0; c < NCLS; c++){
      float x = bp[(size_t)c * HW_];
      va[c] = x; mxv = fmaxf(mxv, x);
      if (c == lab) xlv = x;
    }
    float sev = 0.f;
    #pragma unroll
    for (int c = 0; c < NCLS; c++) sev += __expf(va[c] - mxv);
    float lp = (xlv - mxv) - __logf(sev);
    float pd = __expf(lp);
    keys[p] = (lab != IGNORE_IDX) ? __float_as_uint(pd) : 0xFFFFFFFFu;
    logp[p] = lp;
  }
  __syncthreads();

  unsigned prefix = 0, rank = MIN_KEPT_;        // 1-indexed rank
  #pragma unroll
  for (int rd = 0; rd < 3; rd++){
    const int sh = (rd == 0) ? 20 : (rd == 1) ? 8 : 0;
    const int nb = (rd == 2) ? 8 : 12;
    const unsigned nbin = 1u << nb;
    for (unsigned i = t; i < nbin; i += 1024) s_hist[i] = 0;
    __syncthreads();
    for (int p = t; p < P_TOT; p += 1024){
      unsigned k = keys[p];
      unsigned hi = (rd == 0) ? 0u : (k >> (sh + nb));
      if (hi == prefix) atomicAdd(&s_hist[(k >> sh) & (nbin - 1)], 1u);
    }
    __syncthreads();
    if (t == 0){
      unsigned cum = 0, b = 0;
      for (; b < nbin - 1; b++){
        unsigned cc = s_hist[b];
        if (cum + cc >= rank) break;
        cum += cc;
      }
      s_prefix = (prefix << nb) | b;
      s_rank = rank - cum;
    }
    __syncthreads();
    prefix = s_prefix; rank = s_rank;
    __syncthreads();
  }
  unsigned kb = prefix;                         // bit pattern of kth-smallest pred

  double s = 0.0; unsigned c = 0;
  for (int p = t; p < P_TOT; p += 1024){
    unsigned k = keys[p];
    if (k <= kb){ c++; s += (double)logp[p]; }  // invalid keys (0xFFFFFFFF) excluded
  }
  s = wred_d(s); c = wred_u(c);
  if (ln == 0){ rs1[wv] = s; rc1[wv] = c; }
  __syncthreads();
  if (t == 0){
    double S = 0; unsigned CC = 0;
    for (int i = 0; i < 16; i++){ S += rs1[i]; CC += rc1[i]; }
    unsigned d = CC > 1u ? CC : 1u;
    out[0] = (float)(-S / (double)d);
  }
}

extern "C" void kernel_launch(void* const* d_in, const int* in_sizes, int n_in,
                              void* d_out, int out_size, void* d_ws, size_t ws_size,
                              hipStream_t stream)
{
  const float* logits = (const float*)d_in[0];
  const int*   tgt    = (const int*)d_in[1];
  float* out = (float*)d_out;

  // ws layout: partial sums (96 KB, hot path) then fallback arrays (cold only)
  double*   p_sle = (double*)d_ws;
  double*   p_sva = p_sle + NBLK;
  unsigned* p_cle = (unsigned*)(p_sva + NBLK);
  unsigned* p_cva = p_cle + NBLK;
  unsigned* keys  = p_cva + NBLK;          // P_TOT uints (cold path only)
  float*    logp  = (float*)(keys + P_TOT); // P_TOT floats (cold path only)

  hipLaunchKernelGGL(ohem_pass1, dim3(NBLK), dim3(256), 0, stream,
                     logits, tgt, p_sle, p_sva, p_cle, p_cva);
  hipLaunchKernelGGL(ohem_finish, dim3(1), dim3(1024), 0, stream,
                     logits, tgt, p_sle, p_sva, p_cle, p_cva, keys, logp, out);
}